// Round 1
// 756.132 us; speedup vs baseline: 1.0646x; 1.0646x over previous
//
#include <hip/hip_runtime.h>
#include <math.h>

// ---------------- problem constants (fixed by the reference) ----------------
#define N_TOK 8192      // B*S = 4*2048
#define H_DIM 1024
#define E_NUM 8
#define F_DIM 4096
#define CAP   1280      // ceil(N/E * 1.25) = 10 * 128 exactly
#define NA    (N_TOK*2) // assignments (top-2)
#define KSPLIT 2        // gemm2 split-K factor (640 -> 1280 blocks)

typedef short   short8  __attribute__((ext_vector_type(8)));
typedef float   floatx4 __attribute__((ext_vector_type(4)));

// fp32 -> bf16 round-to-nearest-even
__device__ __forceinline__ unsigned short f2b(float f) {
  unsigned u = __float_as_uint(f);
  unsigned r = (u + 0x7fffu + ((u >> 16) & 1u)) >> 16;
  return (unsigned short)r;
}

// async global->LDS, 16B per lane (LDS dest = wave-uniform base + lane*16)
__device__ __forceinline__ void async_cp16(const void* g, void* l) {
  __builtin_amdgcn_global_load_lds(
      (__attribute__((address_space(1))) void*)(void*)g,
      (__attribute__((address_space(3))) void*)l, 16, 0, 0);
}

// ---------------- K0: transpose + fp32->bf16  src[E][R][C] -> dst[E][C][R] --
// 64x64 tile, 256 threads. Phase1: coalesced float4 loads -> f32 LDS tile
// (row stride 68 dwords: 16B-aligned, bank-spread). Phase2: per-lane 8 scalar
// LDS reads (bank = (c + 4i) % 32, conflict-free) -> cvt -> 16B coalesced store.
__global__ __launch_bounds__(256) void transpose_cvt(const float* __restrict__ src,
                                                     unsigned short* __restrict__ dst,
                                                     int R, int C) {
  __shared__ float tile[64 * 68];
  const int e  = blockIdx.z;
  const int r0 = blockIdx.y * 64, c0 = blockIdx.x * 64;
  const int tid = threadIdx.x;
  const float* s = src + (size_t)e * R * C;
  unsigned short* d = dst + (size_t)e * R * C;
  const int rr = tid >> 4;            // 0..15
  const int c4 = (tid & 15) * 4;      // 0,4,...,60
#pragma unroll
  for (int it = 0; it < 4; ++it) {
    const int r = rr + it * 16;
    const float4 v = *(const float4*)(s + (size_t)(r0 + r) * C + c0 + c4);
    *(float4*)(&tile[r * 68 + c4]) = v;
  }
  __syncthreads();
  const int cc = tid >> 3;            // 0..31
  const int r8 = (tid & 7) * 8;       // 0..56
#pragma unroll
  for (int it = 0; it < 2; ++it) {
    const int c = cc + it * 32;
    uint4 u;
    unsigned short* pu = (unsigned short*)&u;
#pragma unroll
    for (int i = 0; i < 8; ++i) pu[i] = f2b(tile[(r8 + i) * 68 + c]);
    *(uint4*)(d + (size_t)(c0 + c) * R + r0 + r8) = u;
  }
}

// ---------------- K1: router: logits, top-2, softmax ------------------------
// one wave per token
__global__ __launch_bounds__(256) void router_kernel(const float* __restrict__ x,
                                                     const float* __restrict__ Wr,
                                                     const float* __restrict__ br,
                                                     int* __restrict__ eid,
                                                     float* __restrict__ wf) {
  const int token = blockIdx.x * 4 + (threadIdx.x >> 6);
  const int lane  = threadIdx.x & 63;
  const float* xr = x + (size_t)token * H_DIM;
  float acc[E_NUM];
#pragma unroll
  for (int e = 0; e < E_NUM; ++e) acc[e] = 0.f;
  for (int h = lane; h < H_DIM; h += 64) {
    const float xv = xr[h];
    const float* wr = Wr + h * E_NUM;
#pragma unroll
    for (int e = 0; e < E_NUM; ++e) acc[e] += xv * wr[e];
  }
#pragma unroll
  for (int off = 32; off > 0; off >>= 1) {
#pragma unroll
    for (int e = 0; e < E_NUM; ++e) acc[e] += __shfl_down(acc[e], off, 64);
  }
  if (lane == 0) {
#pragma unroll
    for (int e = 0; e < E_NUM; ++e) acc[e] += br[e];
    // top-2, strict > keeps lowest index on ties (matches lax.top_k)
    int i0 = 0;
#pragma unroll
    for (int e = 1; e < E_NUM; ++e) if (acc[e] > acc[i0]) i0 = e;
    int i1 = (i0 == 0) ? 1 : 0;
    for (int e = 0; e < E_NUM; ++e) if (e != i0 && acc[e] > acc[i1]) i1 = e;
    const float ex = expf(acc[i1] - acc[i0]);   // <= 1
    const float inv = 1.f / (1.f + ex);
    eid[token * 2]     = i0;
    eid[token * 2 + 1] = i1;
    wf[token * 2]      = inv;        // softmax of sorted pair
    wf[token * 2 + 1]  = ex * inv;
  }
}

// ---------------- K2: exact per-expert capacity selection -------------------
// radix-select on fp32 bits (all weights > 0 so uint order == float order),
// ties at the threshold broken by lowest assignment index (== lax.top_k).
// 1024 threads: only 8 blocks exist, so widen each block's scan 4x.
#define MAXEQ 4096
__global__ __launch_bounds__(1024) void select_kernel(const int* __restrict__ eid,
                                                      const float* __restrict__ wf,
                                                      int* __restrict__ tok_e,
                                                      float* __restrict__ gate_e) {
  const int e = blockIdx.x;
  const int tid = threadIdx.x;
  __shared__ unsigned hist[256];
  __shared__ unsigned sPrefix, sNeed, sKeepAll, sSlot, eqCnt;
  __shared__ int eq[MAXEQ];
  if (tid == 0) { sPrefix = 0; sNeed = CAP; sKeepAll = 0; sSlot = 0; eqCnt = 0; }
  __syncthreads();
  for (int level = 0; level < 4; ++level) {
    if (tid < 256) hist[tid] = 0;
    __syncthreads();
    const unsigned pref = sPrefix;
    const int shift = 24 - level * 8;
    for (int i = tid; i < NA; i += 1024) {
      if (eid[i] == e) {
        const unsigned wb = __float_as_uint(wf[i]);
        if (level == 0 || (wb >> (shift + 8)) == pref)
          atomicAdd(&hist[(wb >> shift) & 255u], 1u);
      }
    }
    __syncthreads();
    if (tid == 0) {
      const unsigned need = sNeed;
      if (level == 0) {
        unsigned tot = 0;
        for (int b = 0; b < 256; ++b) tot += hist[b];
        if (tot <= (unsigned)CAP) sKeepAll = 1;   // under capacity: keep all
      }
      if (!sKeepAll) {
        unsigned cum = 0; int b = 255;
        for (; b > 0; --b) {
          if (cum + hist[b] >= need) break;
          cum += hist[b];
        }
        sPrefix = (sPrefix << 8) | (unsigned)b;
        sNeed = need - cum;
      }
    }
    __syncthreads();
    if (sKeepAll) break;
  }
  const unsigned keepAll = sKeepAll;
  const unsigned thr = sPrefix;     // exact fp32 bits of the cap-th weight
  for (int i = tid; i < NA; i += 1024) {
    if (eid[i] != e) continue;
    const unsigned wb = __float_as_uint(wf[i]);
    if (keepAll || wb > thr) {
      const unsigned s = atomicAdd(&sSlot, 1u);
      tok_e[e * CAP + s]  = i >> 1;
      gate_e[e * CAP + s] = wf[i];
    } else if (wb == thr) {
      const unsigned p = atomicAdd(&eqCnt, 1u);
      if (p < MAXEQ) eq[p] = i;
    }
  }
  __syncthreads();
  if (!keepAll) {
    const int r = (int)sNeed;                 // how many ties to keep
    const int t = min((int)eqCnt, MAXEQ);
    for (int a2 = tid; a2 < t; a2 += 1024) {
      const int idx = eq[a2];
      int rank = 0;
      for (int b2 = 0; b2 < t; ++b2) rank += (eq[b2] < idx);
      if (rank < r) {
        const unsigned s = atomicAdd(&sSlot, 1u);
        tok_e[e * CAP + s]  = idx >> 1;
        gate_e[e * CAP + s] = wf[idx];
      }
    }
  }
}

// ---------------- K3: gather tokens into per-expert bf16 rows ---------------
__global__ __launch_bounds__(128) void gather_kernel(const float* __restrict__ x,
                                                     const int* __restrict__ tok_e,
                                                     unsigned short* __restrict__ xe) {
  const int s = blockIdx.x;          // global slot in [0, E*CAP)
  const int t = threadIdx.x;         // 128 threads, 8 elems each
  const int tok = tok_e[s];
  uint4* dst = (uint4*)(xe + (size_t)s * H_DIM) + t;
  if (tok < 0) { uint4 z; z.x = z.y = z.z = z.w = 0u; *dst = z; return; }
  const float4* xp = (const float4*)x + (size_t)tok * (H_DIM / 4);
  const float4 v0 = xp[t * 2], v1 = xp[t * 2 + 1];
  uint4 u;
  u.x = (unsigned)f2b(v0.x) | ((unsigned)f2b(v0.y) << 16);
  u.y = (unsigned)f2b(v0.z) | ((unsigned)f2b(v0.w) << 16);
  u.z = (unsigned)f2b(v1.x) | ((unsigned)f2b(v1.y) << 16);
  u.w = (unsigned)f2b(v1.z) | ((unsigned)f2b(v1.w) << 16);
  *dst = u;
}

// ---------------- shared MFMA mainloop (m97 pattern) ------------------------
// C-tile 128x128, BK=32, block=256 (4 waves, each 64x64 = 4x4 MFMA 16x16x32).
// A: [M,K] row-major bf16 (K contiguous, row stride ld); B: B^T [N,K] bf16.
// Computes over K-range [kBeg, kEnd) so callers can split K across blocks.
__device__ __forceinline__ void mfma_loop(const unsigned short* Ab,
                                          const unsigned short* Bb,
                                          int kBeg, int kEnd, int ld,
                                          floatx4 acc[4][4],
                                          unsigned short* As, unsigned short* Bs) {
  const int tid  = threadIdx.x;
  const int lane = tid & 63;
  const int w    = tid >> 6;
  const int wm   = (w >> 1) * 64, wn = (w & 1) * 64;
  const int lrow = lane & 15, lk = (lane >> 4) * 8;
  const int r0 = tid >> 2;                 // staging row for chunk tid
  const int c0 = (tid & 3) * 8;            // staging col (bf16 elems)
  const int r1 = (tid + 256) >> 2;         // chunk tid+256 (same col)
  for (int k0 = kBeg; k0 < kEnd; k0 += 32) {
    async_cp16(Ab + (size_t)r0 * ld + k0 + c0, As + tid * 8);
    async_cp16(Ab + (size_t)r1 * ld + k0 + c0, As + (tid + 256) * 8);
    async_cp16(Bb + (size_t)r0 * ld + k0 + c0, Bs + tid * 8);
    async_cp16(Bb + (size_t)r1 * ld + k0 + c0, Bs + (tid + 256) * 8);
    __syncthreads();                       // compiler drains vmcnt before barrier
    short8 a[4], b[4];
#pragma unroll
    for (int i = 0; i < 4; ++i)
      a[i] = *(const short8*)(As + (wm + i * 16 + lrow) * 32 + lk);
#pragma unroll
    for (int i = 0; i < 4; ++i)
      b[i] = *(const short8*)(Bs + (wn + i * 16 + lrow) * 32 + lk);
#pragma unroll
    for (int mi = 0; mi < 4; ++mi)
#pragma unroll
      for (int ni = 0; ni < 4; ++ni)
        acc[mi][ni] = __builtin_amdgcn_mfma_f32_16x16x32_bf16(a[mi], b[ni], acc[mi][ni], 0, 0, 0);
    __syncthreads();
  }
}

// ---------------- K4: GEMM1  h1 = gelu(xe @ W1 + b1)  (bf16 out) ------------
__global__ __launch_bounds__(256) void gemm1_kernel(const unsigned short* __restrict__ xe,
                                                    const unsigned short* __restrict__ WT,
                                                    const float* __restrict__ b1,
                                                    unsigned short* __restrict__ h1) {
  __shared__ unsigned short As[128 * 32], Bs[128 * 32];
  const int e  = blockIdx.z;
  const int m0 = blockIdx.y * 128, n0 = blockIdx.x * 128;
  const unsigned short* Ab = xe + ((size_t)e * CAP + m0) * H_DIM;
  const unsigned short* Bb = WT + ((size_t)e * F_DIM + n0) * H_DIM;
  floatx4 acc[4][4];
#pragma unroll
  for (int mi = 0; mi < 4; ++mi)
#pragma unroll
    for (int ni = 0; ni < 4; ++ni) acc[mi][ni] = (floatx4){0.f, 0.f, 0.f, 0.f};
  mfma_loop(Ab, Bb, 0, H_DIM, H_DIM, acc, As, Bs);
  const int lane = threadIdx.x & 63, w = threadIdx.x >> 6;
  const int wm = (w >> 1) * 64, wn = (w & 1) * 64;
  const int col0  = n0 + wn + (lane & 15);         // C/D: col = lane&15 (m89)
  const int rbase = m0 + wm + ((lane >> 4) * 4);   // row = (lane>>4)*4 + reg
#pragma unroll
  for (int ni = 0; ni < 4; ++ni) {
    const int col = col0 + ni * 16;
    const float bias = b1[e * F_DIM + col];
#pragma unroll
    for (int mi = 0; mi < 4; ++mi) {
#pragma unroll
      for (int j = 0; j < 4; ++j) {
        const int row = rbase + mi * 16 + j;       // slot within expert
        float v = acc[mi][ni][j] + bias;
        v = 0.5f * v * (1.0f + erff(v * 0.70710678118654752f));  // exact gelu
        h1[((size_t)e * CAP + row) * F_DIM + col] = f2b(v);
      }
    }
  }
}

// ---------------- K6: GEMM2  out[tok] += gate * (h1 @ W2 + b2) --------------
// split-K: grid.z = E_NUM*KSPLIT; chunk kc covers K-range [kc*F/KS, (kc+1)*F/KS).
// Epilogue already atomicAdds into out, so partial K-chunks compose for free;
// bias is added only by the kc==0 chunk.
__global__ __launch_bounds__(256) void gemm2_kernel(const unsigned short* __restrict__ h1,
                                                    const unsigned short* __restrict__ WT,
                                                    const float* __restrict__ b2,
                                                    const int* __restrict__ tok_e,
                                                    const float* __restrict__ gate_e,
                                                    float* __restrict__ out) {
  __shared__ unsigned short As[128 * 32], Bs[128 * 32];
  const int z  = blockIdx.z;
  const int e  = z >> 1;               // KSPLIT == 2
  const int kc = z & 1;
  const int m0 = blockIdx.y * 128, n0 = blockIdx.x * 128;
  const unsigned short* Ab = h1 + ((size_t)e * CAP + m0) * F_DIM;
  const unsigned short* Bb = WT + ((size_t)e * H_DIM + n0) * F_DIM;
  floatx4 acc[4][4];
#pragma unroll
  for (int mi = 0; mi < 4; ++mi)
#pragma unroll
    for (int ni = 0; ni < 4; ++ni) acc[mi][ni] = (floatx4){0.f, 0.f, 0.f, 0.f};
  const int kLen = F_DIM / KSPLIT;
  mfma_loop(Ab, Bb, kc * kLen, kc * kLen + kLen, F_DIM, acc, As, Bs);
  const int lane = threadIdx.x & 63, w = threadIdx.x >> 6;
  const int wm = (w >> 1) * 64, wn = (w & 1) * 64;
  const int col0  = n0 + wn + (lane & 15);
  const int rbase = m0 + wm + ((lane >> 4) * 4);
  float b2v[4];
#pragma unroll
  for (int ni = 0; ni < 4; ++ni)
    b2v[ni] = (kc == 0) ? b2[e * H_DIM + col0 + ni * 16] : 0.f;
#pragma unroll
  for (int mi = 0; mi < 4; ++mi) {
#pragma unroll
    for (int j = 0; j < 4; ++j) {
      const int row = rbase + mi * 16 + j;
      const int tok = tok_e[e * CAP + row];
      if (tok < 0) continue;                        // unused capacity slot
      const float g = gate_e[e * CAP + row];
      float* orow = out + (size_t)tok * H_DIM;
#pragma unroll
      for (int ni = 0; ni < 4; ++ni) {
        const float v = acc[mi][ni][j] + b2v[ni];
        atomicAdd(orow + col0 + ni * 16, g * v);    // <=2 experts * KSPLIT chunks
      }
    }
  }
}

// ---------------- K7: in-place LayerNorm ------------------------------------
__global__ __launch_bounds__(256) void ln_kernel(float* __restrict__ out,
                                                 const float* __restrict__ gamma,
                                                 const float* __restrict__ beta) {
  const int token = blockIdx.x;
  const int tid = threadIdx.x;
  const int lane = tid & 63, w = tid >> 6;
  float* row = out + (size_t)token * H_DIM;
  float v[4];
#pragma unroll
  for (int i = 0; i < 4; ++i) v[i] = row[tid + i * 256];
  float s = v[0] + v[1] + v[2] + v[3];
  __shared__ float red[8];
#pragma unroll
  for (int off = 32; off > 0; off >>= 1) s += __shfl_down(s, off, 64);
  if (lane == 0) red[w] = s;
  __syncthreads();
  const float mu = (red[0] + red[1] + red[2] + red[3]) * (1.f / H_DIM);
  float q = 0.f;
#pragma unroll
  for (int i = 0; i < 4; ++i) { const float d = v[i] - mu; q += d * d; }
#pragma unroll
  for (int off = 32; off > 0; off >>= 1) q += __shfl_down(q, off, 64);
  if (lane == 0) red[4 + w] = q;
  __syncthreads();
  const float var = (red[4] + red[5] + red[6] + red[7]) * (1.f / H_DIM);
  const float rs = rsqrtf(var + 1e-5f);
#pragma unroll
  for (int i = 0; i < 4; ++i) {
    const int h = tid + i * 256;
    row[h] = (v[i] - mu) * rs * gamma[h] + beta[h];
  }
}

// ---------------- launch ----------------------------------------------------
extern "C" void kernel_launch(void* const* d_in, const int* in_sizes, int n_in,
                              void* d_out, int out_size, void* d_ws, size_t ws_size,
                              hipStream_t stream) {
  const float* x     = (const float*)d_in[0];
  const float* Wr    = (const float*)d_in[1];
  const float* br    = (const float*)d_in[2];
  const float* W1    = (const float*)d_in[3];
  const float* b1    = (const float*)d_in[4];
  const float* W2    = (const float*)d_in[5];
  const float* b2    = (const float*)d_in[6];
  const float* gamma = (const float*)d_in[7];
  const float* beta  = (const float*)d_in[8];
  float* out = (float*)d_out;

  // ws layout (bytes). WT region is reused: W1^T for GEMM1, then W2^T for GEMM2.
  char* ws = (char*)d_ws;
  unsigned short* WT   = (unsigned short*)(ws);                 // 67,108,864
  unsigned short* xe   = (unsigned short*)(ws + 67108864);      // 20,971,520
  unsigned short* h1   = (unsigned short*)(ws + 88080384);      // 83,886,080
  int*            eid  = (int*)(ws + 171966464);                // 65,536
  float*          wf   = (float*)(ws + 172032000);              // 65,536
  int*            tok_e  = (int*)(ws + 172097536);              // 40,960
  float*          gate_e = (float*)(ws + 172138496);            // 40,960

  // W1 [E,H,F] -> W1^T bf16 [E,F,H]
  transpose_cvt<<<dim3(F_DIM / 64, H_DIM / 64, E_NUM), 256, 0, stream>>>(W1, WT, H_DIM, F_DIM);
  router_kernel<<<N_TOK / 4, 256, 0, stream>>>(x, Wr, br, eid, wf);
  hipMemsetAsync(tok_e, 0xFF, E_NUM * CAP * sizeof(int), stream);   // -1 = empty
  hipMemsetAsync(gate_e, 0, E_NUM * CAP * sizeof(float), stream);
  select_kernel<<<E_NUM, 1024, 0, stream>>>(eid, wf, tok_e, gate_e);
  gather_kernel<<<E_NUM * CAP, 128, 0, stream>>>(x, tok_e, xe);
  gemm1_kernel<<<dim3(F_DIM / 128, CAP / 128, E_NUM), 256, 0, stream>>>(xe, WT, b1, h1);
  // W2 [E,F,H] -> W2^T bf16 [E,H,F] (reuses WT region; W1^T is dead now)
  transpose_cvt<<<dim3(H_DIM / 64, F_DIM / 64, E_NUM), 256, 0, stream>>>(W2, WT, F_DIM, H_DIM);
  // residual base: out = hidden_states
  hipMemcpyAsync(out, x, (size_t)N_TOK * H_DIM * sizeof(float), hipMemcpyDeviceToDevice, stream);
  gemm2_kernel<<<dim3(H_DIM / 128, CAP / 128, E_NUM * KSPLIT), 256, 0, stream>>>(h1, WT, b2, tok_e, gate_e, out);
  ln_kernel<<<N_TOK, 256, 0, stream>>>(out, gamma, beta);
}

// Round 2
// 712.933 us; speedup vs baseline: 1.1291x; 1.0606x over previous
//
#include <hip/hip_runtime.h>
#include <math.h>

// ---------------- problem constants (fixed by the reference) ----------------
#define N_TOK 8192      // B*S = 4*2048
#define H_DIM 1024
#define E_NUM 8
#define F_DIM 4096
#define CAP   1280      // ceil(N/E * 1.25) = 10 * 128 exactly
#define NA    (N_TOK*2) // assignments (top-2)

typedef short   short8  __attribute__((ext_vector_type(8)));
typedef float   floatx4 __attribute__((ext_vector_type(4)));

// fp32 -> bf16 round-to-nearest-even
__device__ __forceinline__ unsigned short f2b(float f) {
  unsigned u = __float_as_uint(f);
  unsigned r = (u + 0x7fffu + ((u >> 16) & 1u)) >> 16;
  return (unsigned short)r;
}

// async global->LDS, 16B per lane (LDS dest = wave-uniform base + lane*16)
__device__ __forceinline__ void async_cp16(const void* g, void* l) {
  __builtin_amdgcn_global_load_lds(
      (__attribute__((address_space(1))) void*)(void*)g,
      (__attribute__((address_space(3))) void*)l, 16, 0, 0);
}

// ---------------- K0: transpose + fp32->bf16  src[E][R][C] -> dst[E][C][R] --
// 64x64 tile, 256 threads. Phase1: coalesced float4 loads -> f32 LDS tile
// (row stride 68 dwords: 16B-aligned, bank-spread). Phase2: per-lane 8 scalar
// LDS reads (bank = (c + 4i) % 32, conflict-free) -> cvt -> 16B coalesced store.
__global__ __launch_bounds__(256) void transpose_cvt(const float* __restrict__ src,
                                                     unsigned short* __restrict__ dst,
                                                     int R, int C) {
  __shared__ float tile[64 * 68];
  const int e  = blockIdx.z;
  const int r0 = blockIdx.y * 64, c0 = blockIdx.x * 64;
  const int tid = threadIdx.x;
  const float* s = src + (size_t)e * R * C;
  unsigned short* d = dst + (size_t)e * R * C;
  const int rr = tid >> 4;            // 0..15
  const int c4 = (tid & 15) * 4;      // 0,4,...,60
#pragma unroll
  for (int it = 0; it < 4; ++it) {
    const int r = rr + it * 16;
    const float4 v = *(const float4*)(s + (size_t)(r0 + r) * C + c0 + c4);
    *(float4*)(&tile[r * 68 + c4]) = v;
  }
  __syncthreads();
  const int cc = tid >> 3;            // 0..31
  const int r8 = (tid & 7) * 8;       // 0..56
#pragma unroll
  for (int it = 0; it < 2; ++it) {
    const int c = cc + it * 32;
    uint4 u;
    unsigned short* pu = (unsigned short*)&u;
#pragma unroll
    for (int i = 0; i < 8; ++i) pu[i] = f2b(tile[(r8 + i) * 68 + c]);
    *(uint4*)(d + (size_t)(c0 + c) * R + r0 + r8) = u;
  }
}

// ---------------- K1: router: logits, top-2, softmax ------------------------
// one wave per token
__global__ __launch_bounds__(256) void router_kernel(const float* __restrict__ x,
                                                     const float* __restrict__ Wr,
                                                     const float* __restrict__ br,
                                                     int* __restrict__ eid,
                                                     float* __restrict__ wf) {
  const int token = blockIdx.x * 4 + (threadIdx.x >> 6);
  const int lane  = threadIdx.x & 63;
  const float* xr = x + (size_t)token * H_DIM;
  float acc[E_NUM];
#pragma unroll
  for (int e = 0; e < E_NUM; ++e) acc[e] = 0.f;
  for (int h = lane; h < H_DIM; h += 64) {
    const float xv = xr[h];
    const float* wr = Wr + h * E_NUM;
#pragma unroll
    for (int e = 0; e < E_NUM; ++e) acc[e] += xv * wr[e];
  }
#pragma unroll
  for (int off = 32; off > 0; off >>= 1) {
#pragma unroll
    for (int e = 0; e < E_NUM; ++e) acc[e] += __shfl_down(acc[e], off, 64);
  }
  if (lane == 0) {
#pragma unroll
    for (int e = 0; e < E_NUM; ++e) acc[e] += br[e];
    // top-2, strict > keeps lowest index on ties (matches lax.top_k)
    int i0 = 0;
#pragma unroll
    for (int e = 1; e < E_NUM; ++e) if (acc[e] > acc[i0]) i0 = e;
    int i1 = (i0 == 0) ? 1 : 0;
    for (int e = 0; e < E_NUM; ++e) if (e != i0 && acc[e] > acc[i1]) i1 = e;
    const float ex = expf(acc[i1] - acc[i0]);   // <= 1
    const float inv = 1.f / (1.f + ex);
    eid[token * 2]     = i0;
    eid[token * 2 + 1] = i1;
    wf[token * 2]      = inv;        // softmax of sorted pair
    wf[token * 2 + 1]  = ex * inv;
  }
}

// ---------------- K2: exact per-expert capacity selection -------------------
// radix-select on fp32 bits (all weights > 0 so uint order == float order),
// ties at the threshold broken by lowest assignment index (== lax.top_k).
// Also emits the inverse map slot_of[assignment] -> e*CAP+slot (or -1 dropped)
// so the combine stage needs no atomics.
#define MAXEQ 4096
__global__ __launch_bounds__(1024) void select_kernel(const int* __restrict__ eid,
                                                      const float* __restrict__ wf,
                                                      int* __restrict__ tok_e,
                                                      float* __restrict__ gate_e,
                                                      int* __restrict__ slot_of) {
  const int e = blockIdx.x;
  const int tid = threadIdx.x;
  __shared__ unsigned hist[256];
  __shared__ unsigned sPrefix, sNeed, sKeepAll, sSlot, eqCnt;
  __shared__ int eq[MAXEQ];
  if (tid == 0) { sPrefix = 0; sNeed = CAP; sKeepAll = 0; sSlot = 0; eqCnt = 0; }
  __syncthreads();
  for (int level = 0; level < 4; ++level) {
    if (tid < 256) hist[tid] = 0;
    __syncthreads();
    const unsigned pref = sPrefix;
    const int shift = 24 - level * 8;
    for (int i = tid; i < NA; i += 1024) {
      if (eid[i] == e) {
        const unsigned wb = __float_as_uint(wf[i]);
        if (level == 0 || (wb >> (shift + 8)) == pref)
          atomicAdd(&hist[(wb >> shift) & 255u], 1u);
      }
    }
    __syncthreads();
    if (tid == 0) {
      const unsigned need = sNeed;
      if (level == 0) {
        unsigned tot = 0;
        for (int b = 0; b < 256; ++b) tot += hist[b];
        if (tot <= (unsigned)CAP) sKeepAll = 1;   // under capacity: keep all
      }
      if (!sKeepAll) {
        unsigned cum = 0; int b = 255;
        for (; b > 0; --b) {
          if (cum + hist[b] >= need) break;
          cum += hist[b];
        }
        sPrefix = (sPrefix << 8) | (unsigned)b;
        sNeed = need - cum;
      }
    }
    __syncthreads();
    if (sKeepAll) break;
  }
  const unsigned keepAll = sKeepAll;
  const unsigned thr = sPrefix;     // exact fp32 bits of the cap-th weight
  for (int i = tid; i < NA; i += 1024) {
    if (eid[i] != e) continue;
    const unsigned wb = __float_as_uint(wf[i]);
    if (keepAll || wb > thr) {
      const unsigned s = atomicAdd(&sSlot, 1u);
      tok_e[e * CAP + s]  = i >> 1;
      gate_e[e * CAP + s] = wf[i];
      if (slot_of) slot_of[i] = e * CAP + (int)s;
    } else if (wb == thr) {
      const unsigned p = atomicAdd(&eqCnt, 1u);
      if (p < MAXEQ) eq[p] = i;
    }
  }
  __syncthreads();
  if (!keepAll) {
    const int r = (int)sNeed;                 // how many ties to keep
    const int t = min((int)eqCnt, MAXEQ);
    for (int a2 = tid; a2 < t; a2 += 1024) {
      const int idx = eq[a2];
      int rank = 0;
      for (int b2 = 0; b2 < t; ++b2) rank += (eq[b2] < idx);
      if (rank < r) {
        const unsigned s = atomicAdd(&sSlot, 1u);
        tok_e[e * CAP + s]  = idx >> 1;
        gate_e[e * CAP + s] = wf[idx];
        if (slot_of) slot_of[idx] = e * CAP + (int)s;
      }
    }
  }
}

// ---------------- K3: gather tokens into per-expert bf16 rows ---------------
__global__ __launch_bounds__(128) void gather_kernel(const float* __restrict__ x,
                                                     const int* __restrict__ tok_e,
                                                     unsigned short* __restrict__ xe) {
  const int s = blockIdx.x;          // global slot in [0, E*CAP)
  const int t = threadIdx.x;         // 128 threads, 8 elems each
  const int tok = tok_e[s];
  uint4* dst = (uint4*)(xe + (size_t)s * H_DIM) + t;
  if (tok < 0) { uint4 z; z.x = z.y = z.z = z.w = 0u; *dst = z; return; }
  const float4* xp = (const float4*)x + (size_t)tok * (H_DIM / 4);
  const float4 v0 = xp[t * 2], v1 = xp[t * 2 + 1];
  uint4 u;
  u.x = (unsigned)f2b(v0.x) | ((unsigned)f2b(v0.y) << 16);
  u.y = (unsigned)f2b(v0.z) | ((unsigned)f2b(v0.w) << 16);
  u.z = (unsigned)f2b(v1.x) | ((unsigned)f2b(v1.y) << 16);
  u.w = (unsigned)f2b(v1.z) | ((unsigned)f2b(v1.w) << 16);
  *dst = u;
}

// ---------------- shared MFMA mainloop (m97 pattern) ------------------------
// C-tile 128x128, BK=32, block=256 (4 waves, each 64x64 = 4x4 MFMA 16x16x32).
// A: [M,K] row-major bf16 (K contiguous, row stride ld); B: B^T [N,K] bf16.
__device__ __forceinline__ void mfma_loop(const unsigned short* Ab,
                                          const unsigned short* Bb,
                                          int Kdim, int ld,
                                          floatx4 acc[4][4],
                                          unsigned short* As, unsigned short* Bs) {
  const int tid  = threadIdx.x;
  const int lane = tid & 63;
  const int w    = tid >> 6;
  const int wm   = (w >> 1) * 64, wn = (w & 1) * 64;
  const int lrow = lane & 15, lk = (lane >> 4) * 8;
  const int r0 = tid >> 2;                 // staging row for chunk tid
  const int c0 = (tid & 3) * 8;            // staging col (bf16 elems)
  const int r1 = (tid + 256) >> 2;         // chunk tid+256 (same col)
  for (int k0 = 0; k0 < Kdim; k0 += 32) {
    async_cp16(Ab + (size_t)r0 * ld + k0 + c0, As + tid * 8);
    async_cp16(Ab + (size_t)r1 * ld + k0 + c0, As + (tid + 256) * 8);
    async_cp16(Bb + (size_t)r0 * ld + k0 + c0, Bs + tid * 8);
    async_cp16(Bb + (size_t)r1 * ld + k0 + c0, Bs + (tid + 256) * 8);
    __syncthreads();                       // compiler drains vmcnt before barrier
    short8 a[4], b[4];
#pragma unroll
    for (int i = 0; i < 4; ++i)
      a[i] = *(const short8*)(As + (wm + i * 16 + lrow) * 32 + lk);
#pragma unroll
    for (int i = 0; i < 4; ++i)
      b[i] = *(const short8*)(Bs + (wn + i * 16 + lrow) * 32 + lk);
#pragma unroll
    for (int mi = 0; mi < 4; ++mi)
#pragma unroll
      for (int ni = 0; ni < 4; ++ni)
        acc[mi][ni] = __builtin_amdgcn_mfma_f32_16x16x32_bf16(a[mi], b[ni], acc[mi][ni], 0, 0, 0);
    __syncthreads();
  }
}

// ---------------- K4: GEMM1  h1 = gelu(xe @ W1 + b1)  (bf16 out) ------------
__global__ __launch_bounds__(256) void gemm1_kernel(const unsigned short* __restrict__ xe,
                                                    const unsigned short* __restrict__ WT,
                                                    const float* __restrict__ b1,
                                                    unsigned short* __restrict__ h1) {
  __shared__ unsigned short As[128 * 32], Bs[128 * 32];
  const int e  = blockIdx.z;
  const int m0 = blockIdx.y * 128, n0 = blockIdx.x * 128;
  const unsigned short* Ab = xe + ((size_t)e * CAP + m0) * H_DIM;
  const unsigned short* Bb = WT + ((size_t)e * F_DIM + n0) * H_DIM;
  floatx4 acc[4][4];
#pragma unroll
  for (int mi = 0; mi < 4; ++mi)
#pragma unroll
    for (int ni = 0; ni < 4; ++ni) acc[mi][ni] = (floatx4){0.f, 0.f, 0.f, 0.f};
  mfma_loop(Ab, Bb, H_DIM, H_DIM, acc, As, Bs);
  const int lane = threadIdx.x & 63, w = threadIdx.x >> 6;
  const int wm = (w >> 1) * 64, wn = (w & 1) * 64;
  const int col0  = n0 + wn + (lane & 15);         // C/D: col = lane&15 (m89)
  const int rbase = m0 + wm + ((lane >> 4) * 4);   // row = (lane>>4)*4 + reg
#pragma unroll
  for (int ni = 0; ni < 4; ++ni) {
    const int col = col0 + ni * 16;
    const float bias = b1[e * F_DIM + col];
#pragma unroll
    for (int mi = 0; mi < 4; ++mi) {
#pragma unroll
      for (int j = 0; j < 4; ++j) {
        const int row = rbase + mi * 16 + j;       // slot within expert
        float v = acc[mi][ni][j] + bias;
        v = 0.5f * v * (1.0f + erff(v * 0.70710678118654752f));  // exact gelu
        h1[((size_t)e * CAP + row) * F_DIM + col] = f2b(v);
      }
    }
  }
}

// ---------------- K6a: GEMM2 (y path)  y[slot] = h1 @ W2 + b2 ---------------
// Plain f32 stores, no atomics; gate/combine applied later per token.
__global__ __launch_bounds__(256) void gemm2_y_kernel(const unsigned short* __restrict__ h1,
                                                      const unsigned short* __restrict__ WT,
                                                      const float* __restrict__ b2,
                                                      float* __restrict__ y) {
  __shared__ unsigned short As[128 * 32], Bs[128 * 32];
  const int e  = blockIdx.z;
  const int m0 = blockIdx.y * 128, n0 = blockIdx.x * 128;
  const unsigned short* Ab = h1 + ((size_t)e * CAP + m0) * F_DIM;
  const unsigned short* Bb = WT + ((size_t)e * H_DIM + n0) * F_DIM;
  floatx4 acc[4][4];
#pragma unroll
  for (int mi = 0; mi < 4; ++mi)
#pragma unroll
    for (int ni = 0; ni < 4; ++ni) acc[mi][ni] = (floatx4){0.f, 0.f, 0.f, 0.f};
  mfma_loop(Ab, Bb, F_DIM, F_DIM, acc, As, Bs);
  const int lane = threadIdx.x & 63, w = threadIdx.x >> 6;
  const int wm = (w >> 1) * 64, wn = (w & 1) * 64;
  const int col0  = n0 + wn + (lane & 15);
  const int rbase = m0 + wm + ((lane >> 4) * 4);
  float b2v[4];
#pragma unroll
  for (int ni = 0; ni < 4; ++ni) b2v[ni] = b2[e * H_DIM + col0 + ni * 16];
#pragma unroll
  for (int mi = 0; mi < 4; ++mi) {
#pragma unroll
    for (int j = 0; j < 4; ++j) {
      const int row = rbase + mi * 16 + j;        // slot within expert
      float* yr = y + ((size_t)e * CAP + row) * H_DIM;
#pragma unroll
      for (int ni = 0; ni < 4; ++ni)
        yr[col0 + ni * 16] = acc[mi][ni][j] + b2v[ni];
    }
  }
}

// ---------------- K6b: GEMM2 (atomic fallback, ws too small) ----------------
__global__ __launch_bounds__(256) void gemm2_atomic_kernel(const unsigned short* __restrict__ h1,
                                                           const unsigned short* __restrict__ WT,
                                                           const float* __restrict__ b2,
                                                           const int* __restrict__ tok_e,
                                                           const float* __restrict__ gate_e,
                                                           float* __restrict__ out) {
  __shared__ unsigned short As[128 * 32], Bs[128 * 32];
  const int e  = blockIdx.z;
  const int m0 = blockIdx.y * 128, n0 = blockIdx.x * 128;
  const unsigned short* Ab = h1 + ((size_t)e * CAP + m0) * F_DIM;
  const unsigned short* Bb = WT + ((size_t)e * H_DIM + n0) * F_DIM;
  floatx4 acc[4][4];
#pragma unroll
  for (int mi = 0; mi < 4; ++mi)
#pragma unroll
    for (int ni = 0; ni < 4; ++ni) acc[mi][ni] = (floatx4){0.f, 0.f, 0.f, 0.f};
  mfma_loop(Ab, Bb, F_DIM, F_DIM, acc, As, Bs);
  const int lane = threadIdx.x & 63, w = threadIdx.x >> 6;
  const int wm = (w >> 1) * 64, wn = (w & 1) * 64;
  const int col0  = n0 + wn + (lane & 15);
  const int rbase = m0 + wm + ((lane >> 4) * 4);
  float b2v[4];
#pragma unroll
  for (int ni = 0; ni < 4; ++ni) b2v[ni] = b2[e * H_DIM + col0 + ni * 16];
#pragma unroll
  for (int mi = 0; mi < 4; ++mi) {
#pragma unroll
    for (int j = 0; j < 4; ++j) {
      const int row = rbase + mi * 16 + j;
      const int tok = tok_e[e * CAP + row];
      if (tok < 0) continue;
      const float g = gate_e[e * CAP + row];
      float* orow = out + (size_t)tok * H_DIM;
#pragma unroll
      for (int ni = 0; ni < 4; ++ni) {
        const float v = acc[mi][ni][j] + b2v[ni];
        atomicAdd(orow + col0 + ni * 16, g * v);
      }
    }
  }
}

// ---------------- K7a: fused combine + residual + LayerNorm (y path) --------
// out[t] = LN(x[t] + g0*y[s0] + g1*y[s1]); slots from the inverse map.
__global__ __launch_bounds__(256) void combine_ln_kernel(const float* __restrict__ x,
                                                         const float* __restrict__ y,
                                                         const int* __restrict__ slot_of,
                                                         const float* __restrict__ wf,
                                                         const float* __restrict__ gamma,
                                                         const float* __restrict__ beta,
                                                         float* __restrict__ out) {
  const int token = blockIdx.x;
  const int tid = threadIdx.x;
  const int lane = tid & 63, w = tid >> 6;
  const int s0 = slot_of[token * 2], s1 = slot_of[token * 2 + 1];
  const float g0 = wf[token * 2], g1 = wf[token * 2 + 1];
  const float* xr = x + (size_t)token * H_DIM;
  const float* y0 = y + (size_t)(s0 < 0 ? 0 : s0) * H_DIM;
  const float* y1 = y + (size_t)(s1 < 0 ? 0 : s1) * H_DIM;
  float v[4];
#pragma unroll
  for (int i = 0; i < 4; ++i) {
    const int h = tid + i * 256;
    float a = xr[h];
    if (s0 >= 0) a += g0 * y0[h];     // block-uniform branch
    if (s1 >= 0) a += g1 * y1[h];
    v[i] = a;
  }
  float s = v[0] + v[1] + v[2] + v[3];
  __shared__ float red[8];
#pragma unroll
  for (int off = 32; off > 0; off >>= 1) s += __shfl_down(s, off, 64);
  if (lane == 0) red[w] = s;
  __syncthreads();
  const float mu = (red[0] + red[1] + red[2] + red[3]) * (1.f / H_DIM);
  float q = 0.f;
#pragma unroll
  for (int i = 0; i < 4; ++i) { const float d = v[i] - mu; q += d * d; }
#pragma unroll
  for (int off = 32; off > 0; off >>= 1) q += __shfl_down(q, off, 64);
  if (lane == 0) red[4 + w] = q;
  __syncthreads();
  const float var = (red[4] + red[5] + red[6] + red[7]) * (1.f / H_DIM);
  const float rs = rsqrtf(var + 1e-5f);
  float* orow = out + (size_t)token * H_DIM;
#pragma unroll
  for (int i = 0; i < 4; ++i) {
    const int h = tid + i * 256;
    orow[h] = (v[i] - mu) * rs * gamma[h] + beta[h];
  }
}

// ---------------- K7b: in-place LayerNorm (atomic fallback path) ------------
__global__ __launch_bounds__(256) void ln_kernel(float* __restrict__ out,
                                                 const float* __restrict__ gamma,
                                                 const float* __restrict__ beta) {
  const int token = blockIdx.x;
  const int tid = threadIdx.x;
  const int lane = tid & 63, w = tid >> 6;
  float* row = out + (size_t)token * H_DIM;
  float v[4];
#pragma unroll
  for (int i = 0; i < 4; ++i) v[i] = row[tid + i * 256];
  float s = v[0] + v[1] + v[2] + v[3];
  __shared__ float red[8];
#pragma unroll
  for (int off = 32; off > 0; off >>= 1) s += __shfl_down(s, off, 64);
  if (lane == 0) red[w] = s;
  __syncthreads();
  const float mu = (red[0] + red[1] + red[2] + red[3]) * (1.f / H_DIM);
  float q = 0.f;
#pragma unroll
  for (int i = 0; i < 4; ++i) { const float d = v[i] - mu; q += d * d; }
#pragma unroll
  for (int off = 32; off > 0; off >>= 1) q += __shfl_down(q, off, 64);
  if (lane == 0) red[4 + w] = q;
  __syncthreads();
  const float var = (red[4] + red[5] + red[6] + red[7]) * (1.f / H_DIM);
  const float rs = rsqrtf(var + 1e-5f);
#pragma unroll
  for (int i = 0; i < 4; ++i) {
    const int h = tid + i * 256;
    row[h] = (v[i] - mu) * rs * gamma[h] + beta[h];
  }
}

// ---------------- launch ----------------------------------------------------
extern "C" void kernel_launch(void* const* d_in, const int* in_sizes, int n_in,
                              void* d_out, int out_size, void* d_ws, size_t ws_size,
                              hipStream_t stream) {
  const float* x     = (const float*)d_in[0];
  const float* Wr    = (const float*)d_in[1];
  const float* br    = (const float*)d_in[2];
  const float* W1    = (const float*)d_in[3];
  const float* b1    = (const float*)d_in[4];
  const float* W2    = (const float*)d_in[5];
  const float* b2    = (const float*)d_in[6];
  const float* gamma = (const float*)d_in[7];
  const float* beta  = (const float*)d_in[8];
  float* out = (float*)d_out;

  // ws layout (bytes). WT region is reused: W1^T for GEMM1, then W2^T for GEMM2.
  char* ws = (char*)d_ws;
  unsigned short* WT   = (unsigned short*)(ws);                 //  67,108,864
  unsigned short* xe   = (unsigned short*)(ws + 67108864);      //  20,971,520
  unsigned short* h1   = (unsigned short*)(ws + 88080384);      //  83,886,080
  int*            eid  = (int*)(ws + 171966464);                //  65,536
  float*          wf   = (float*)(ws + 172032000);              //  65,536
  int*            tok_e  = (int*)(ws + 172097536);              //  40,960
  float*          gate_e = (float*)(ws + 172138496);            //  40,960
  int*            slot_of = (int*)(ws + 172179456);             //  65,536
  float*          y    = (float*)(ws + 172244992);              //  41,943,040 -> end 214,188,032
  const int use_y = (ws_size >= (size_t)214188032);
  const int have_slot = (ws_size >= (size_t)172244992);

  // W1 [E,H,F] -> W1^T bf16 [E,F,H]
  transpose_cvt<<<dim3(F_DIM / 64, H_DIM / 64, E_NUM), 256, 0, stream>>>(W1, WT, H_DIM, F_DIM);
  router_kernel<<<N_TOK / 4, 256, 0, stream>>>(x, Wr, br, eid, wf);
  hipMemsetAsync(tok_e, 0xFF, E_NUM * CAP * sizeof(int), stream);   // -1 = empty
  hipMemsetAsync(gate_e, 0, E_NUM * CAP * sizeof(float), stream);
  if (have_slot) hipMemsetAsync(slot_of, 0xFF, NA * sizeof(int), stream);  // -1 = dropped
  select_kernel<<<E_NUM, 1024, 0, stream>>>(eid, wf, tok_e, gate_e,
                                            have_slot ? slot_of : (int*)nullptr);
  gather_kernel<<<E_NUM * CAP, 128, 0, stream>>>(x, tok_e, xe);
  gemm1_kernel<<<dim3(F_DIM / 128, CAP / 128, E_NUM), 256, 0, stream>>>(xe, WT, b1, h1);
  // W2 [E,F,H] -> W2^T bf16 [E,H,F] (reuses WT region; W1^T is dead now)
  transpose_cvt<<<dim3(H_DIM / 64, F_DIM / 64, E_NUM), 256, 0, stream>>>(W2, WT, F_DIM, H_DIM);
  if (use_y) {
    // no atomics, no residual memcpy: gemm2 -> y, then fused combine+LN
    gemm2_y_kernel<<<dim3(H_DIM / 128, CAP / 128, E_NUM), 256, 0, stream>>>(h1, WT, b2, y);
    combine_ln_kernel<<<N_TOK, 256, 0, stream>>>(x, y, slot_of, wf, gamma, beta, out);
  } else {
    hipMemcpyAsync(out, x, (size_t)N_TOK * H_DIM * sizeof(float), hipMemcpyDeviceToDevice, stream);
    gemm2_atomic_kernel<<<dim3(H_DIM / 128, CAP / 128, E_NUM), 256, 0, stream>>>(h1, WT, b2, tok_e, gate_e, out);
    ln_kernel<<<N_TOK, 256, 0, stream>>>(out, gamma, beta);
  }
}